// Round 8
// baseline (562.249 us; speedup 1.0000x reference)
//
#include <hip/hip_runtime.h>
#include <hip/hip_bf16.h>
#include <math.h>

#define NFM 512   // NFMODES
#define NE  256
#define NUN 32    // NUNPAIRED
#define NM  480   // NMODES
#define NB  32    // BATCH
#define NF  288   // NE + NUN  (Ffull dim)
#define WP  16    // panel width
#define PAIRS 8   // WP/2
#define PP  17    // panel LDS pitch (odd -> conflict-free)
#define THETA 0.03125f

typedef unsigned long long ull;

// ---------------- Ja = (J - J^T)/2 ----------------
__global__ __launch_bounds__(256)
void build_ja_k(const float* __restrict__ J, float* __restrict__ Ja) {
  int t = blockIdx.x * blockDim.x + threadIdx.x;
  int stride = gridDim.x * blockDim.x;
  for (int e = t; e < NM * NM; e += stride) {
    int i = e / NM, j = e - i * NM;
    Ja[e] = 0.5f * (J[i * NM + j] - J[j * NM + i]);
  }
}

// ---------------- Tmp[b] (256x480) = Up_b @ Ja ----------
__global__ __launch_bounds__(256)
void gemm1_k(const float* __restrict__ U, const int* __restrict__ idx,
             const float* __restrict__ Ja, float* __restrict__ Tmp) {
  const int b  = blockIdx.z;
  const int m0 = blockIdx.y << 6;
  const int n0 = blockIdx.x << 6;
  const int tid = threadIdx.x;
  __shared__ float As[16][64];
  __shared__ float Bs[16][64];
  const int ar = tid >> 2, ac = (tid & 3) << 2;
  const int br = tid >> 4, bc = (tid & 15) << 2;
  const int tx = tid & 15, ty = tid >> 4;
  const float* Arow = U + (size_t)idx[b * NE + m0 + ar] * NFM + NUN;
  float acc[4][4] = {};
  for (int l0 = 0; l0 < NM; l0 += 16) {
    float4 av = *(const float4*)(Arow + l0 + ac);
    As[ac + 0][ar] = av.x; As[ac + 1][ar] = av.y;
    As[ac + 2][ar] = av.z; As[ac + 3][ar] = av.w;
    float4 bv = make_float4(0.f, 0.f, 0.f, 0.f);
    if (n0 + bc < NM) bv = *(const float4*)(Ja + (size_t)(l0 + br) * NM + n0 + bc);
    *(float4*)(&Bs[br][bc]) = bv;
    __syncthreads();
#pragma unroll
    for (int kk = 0; kk < 16; ++kk) {
      float4 a4 = *(const float4*)(&As[kk][ty << 2]);
      float4 b4 = *(const float4*)(&Bs[kk][tx << 2]);
      float a[4] = {a4.x, a4.y, a4.z, a4.w};
      float bb[4] = {b4.x, b4.y, b4.z, b4.w};
#pragma unroll
      for (int q = 0; q < 4; ++q)
#pragma unroll
        for (int p = 0; p < 4; ++p) acc[q][p] = fmaf(a[q], bb[p], acc[q][p]);
    }
    __syncthreads();
  }
  float* Tb = Tmp + (size_t)b * NE * NM;
#pragma unroll
  for (int q = 0; q < 4; ++q) {
    int r = m0 + (ty << 2) + q;
#pragma unroll
    for (int p = 0; p < 4; ++p) {
      int m = n0 + (tx << 2) + p;
      if (m < NM) Tb[(size_t)r * NM + m] = acc[q][p];
    }
  }
}

// ---------------- F[b] = Tmp[b] @ Up_b^T  -> Ffull[0:256][0:256] ------------
__global__ __launch_bounds__(256)
void gemm2_k(const float* __restrict__ U, const int* __restrict__ idx,
             const float* __restrict__ Tmp, float* __restrict__ Ff) {
  const int b  = blockIdx.z;
  const int m0 = blockIdx.y << 6;
  const int n0 = blockIdx.x << 6;
  const int tid = threadIdx.x;
  __shared__ float As[16][64];
  __shared__ float Bs[16][64];
  const int ar = tid >> 2, ac = (tid & 3) << 2;
  const int jr = tid >> 2, kc = (tid & 3) << 2;
  const int tx = tid & 15, ty = tid >> 4;
  const float* Arow = Tmp + ((size_t)b * NE + m0 + ar) * NM;
  const float* Brow = U + (size_t)idx[b * NE + n0 + jr] * NFM + NUN;
  float acc[4][4] = {};
  for (int l0 = 0; l0 < NM; l0 += 16) {
    float4 av = *(const float4*)(Arow + l0 + ac);
    As[ac + 0][ar] = av.x; As[ac + 1][ar] = av.y;
    As[ac + 2][ar] = av.z; As[ac + 3][ar] = av.w;
    float4 bv = *(const float4*)(Brow + l0 + kc);
    Bs[kc + 0][jr] = bv.x; Bs[kc + 1][jr] = bv.y;
    Bs[kc + 2][jr] = bv.z; Bs[kc + 3][jr] = bv.w;
    __syncthreads();
#pragma unroll
    for (int kk = 0; kk < 16; ++kk) {
      float4 a4 = *(const float4*)(&As[kk][ty << 2]);
      float4 b4 = *(const float4*)(&Bs[kk][tx << 2]);
      float a[4] = {a4.x, a4.y, a4.z, a4.w};
      float bb[4] = {b4.x, b4.y, b4.z, b4.w};
#pragma unroll
      for (int q = 0; q < 4; ++q)
#pragma unroll
        for (int p = 0; p < 4; ++p) acc[q][p] = fmaf(a[q], bb[p], acc[q][p]);
    }
    __syncthreads();
  }
  float* Fb = Ff + (size_t)b * NF * NF;
#pragma unroll
  for (int q = 0; q < 4; ++q) {
    int i = m0 + (ty << 2) + q;
#pragma unroll
    for (int p = 0; p < 4; ++p) {
      int j = n0 + (tx << 2) + p;
      Fb[(size_t)i * NF + j] = acc[q][p];
    }
  }
}

// ---------------- edges ---------------
__global__ __launch_bounds__(256)
void fill_edges_k(const float* __restrict__ U, const int* __restrict__ idx,
                  float* __restrict__ Ff) {
  const int b = blockIdx.x;
  const int tid = threadIdx.x;
  float* Fb = Ff + (size_t)b * NF * NF;
  const int gr = idx[b * NE + tid];
#pragma unroll 4
  for (int u = 0; u < NUN; ++u) {
    float v = U[(size_t)gr * NFM + u];
    Fb[(size_t)tid * NF + NE + u] = v;
    Fb[(size_t)(NE + u) * NF + tid] = -v;
  }
  if (tid < NUN) {
    for (int v = 0; v < NUN; ++v) Fb[(size_t)(NE + tid) * NF + NE + v] = 0.f;
  }
}

// ---------------- Pfaffian: blocked Parlett-Reid, threshold pivoting --------
// Invariant: A_cur[i][j] = snapshot[i][j] + sum_m iv[m]*(nu_m[i]c_m[j]-c_m[i]nu_m[j])
// snapshot = P (panel cols, LDS) + global A (trailing cols). nu = -A_cur[:,k],
// tau = nu*iv. Common step: speculative stage pre-B1 -> ONE barrier.
// Swap steps (rare under threshold): round-6-verified algebra, 3 barriers.
// Trailing: j-outer register-cached rank-8 x2 half-passes.
__global__ __launch_bounds__(512)
void pfpanel_k(float* __restrict__ Ff, float* __restrict__ out) {
  const int b = blockIdx.x;
  float* __restrict__ A = Ff + (size_t)b * NF * NF;
  const int tid = threadIdx.x;
  __shared__ __align__(16) float P[NF * PP];
  __shared__ __align__(16) float s_nu[PAIRS][NF];
  __shared__ __align__(16) float s_c[PAIRS][NF];
  __shared__ __align__(16) float s_colbuf[NF];
  __shared__ float s_oldrow[WP];
  __shared__ float s_pivdef[2];
  __shared__ ull s_red[2][8];

  float sign = 1.f, logabs = 0.f;   // thread 0 only
  float iv[PAIRS];                  // uniform per-pair 1/pivot (all threads)

#pragma unroll 1
  for (int k0 = 0; k0 < NF; k0 += WP) {
    const int pend = k0 + WP;

    // ---- panel load: P[r][0..15] = A[r][k0..k0+15] ----
    for (int e = tid; e < NF * 4; e += 512) {
      int r = e >> 2, c4 = (e & 3) << 2;
      float4 v = *(const float4*)(A + (size_t)r * NF + k0 + c4);
      float* d = P + r * PP + c4;
      d[0] = v.x; d[1] = v.y; d[2] = v.z; d[3] = v.w;
    }
    __syncthreads();

#pragma unroll
    for (int mp = 0; mp < PAIRS; ++mp) {
      const int k = k0 + 2 * mp, lc = 2 * mp, lc1 = lc + 1;
      const int par = mp & 1;

      // ---- phase 1: pair columns + corrections, speculative stage, max ----
      float vk = 0.f, vk1 = 0.f;
      ull pk = 0;
      if (tid > k && tid < NF) {
        vk = P[tid * PP + lc];
        vk1 = P[tid * PP + lc1];
#pragma unroll
        for (int m = 0; m < mp; ++m) {
          float nu_i = s_nu[m][tid], c_i = s_c[m][tid];
          float im = iv[m];
          vk  = fmaf(nu_i, im * s_c[m][k],     fmaf(-c_i, im * s_nu[m][k],     vk));
          vk1 = fmaf(nu_i, im * s_c[m][k + 1], fmaf(-c_i, im * s_nu[m][k + 1], vk1));
        }
        s_colbuf[tid] = vk;
        if (tid > k + 1) { s_nu[mp][tid] = -vk; s_c[mp][tid] = vk1; }
        else             s_pivdef[par] = vk;    // tid == k+1
        pk = ((ull)__float_as_uint(fabsf(vk)) << 32) | (ull)(NF - tid);
      }
#pragma unroll
      for (int m = 32; m > 0; m >>= 1) {
        ull o = __shfl_xor(pk, m, 64);
        if (o > pk) pk = o;
      }
      if ((tid & 63) == 0) s_red[par][tid >> 6] = pk;
      __syncthreads();                                   // B1
      ull best = s_red[par][0];
#pragma unroll
      for (int w = 1; w < 8; ++w) if (s_red[par][w] > best) best = s_red[par][w];
      const float vmax = __uint_as_float((unsigned)(best >> 32));
      const float pivdef_raw = s_pivdef[par];
      const bool doswap = fabsf(pivdef_raw) < THETA * vmax;
      const int kp = doswap ? (NF - (int)(best & 0xffffffffULL)) : (k + 1);
      const float pivot = doswap ? -s_colbuf[kp] : -pivdef_raw;
      const float invp = 1.f / pivot;
      iv[mp] = invp;
      if (tid == 0) {
        if (doswap) sign = -sign;
        sign *= (pivot > 0.f ? 1.f : (pivot < 0.f ? -1.f : 0.f));
        logabs += logf(fabsf(pivot));
      }

      if (doswap) {
        const bool inpanel = (kp < pend);
        const int lckp = kp - k0;
        float gvr = 0.f;
        if (inpanel) {
          // ---- case B: in-panel swap (LDS only) ----
          if (tid > k + 1 && tid < NF && tid != kp) {
            float a1 = P[tid * PP + lc1], a2 = P[tid * PP + lckp];
            P[tid * PP + lc1] = a2; P[tid * PP + lckp] = a1;
          } else if (tid >= NF && tid < NF + WP) {
            int c = tid - NF;
            if (c != lc1 && c != lckp) {
              float a1 = P[(k + 1) * PP + c], a2 = P[kp * PP + c];
              P[(k + 1) * PP + c] = a2; P[kp * PP + c] = a1;
            }
          } else if (tid == NF + WP) {
            float a1 = P[kp * PP + lc1];        // old A[kp][k+1]
            float a2 = P[(k + 1) * PP + lckp];  // old A[k+1][kp]
            P[(k + 1) * PP + lc1] = 0.f;  P[(k + 1) * PP + lckp] = a1;
            P[kp * PP + lc1] = a2;        P[kp * PP + lckp] = 0.f;
          } else if (tid >= NF + 24 && tid < NF + 24 + mp) {
            int m = tid - (NF + 24);
            float a1 = s_nu[m][k + 1]; s_nu[m][k + 1] = s_nu[m][kp]; s_nu[m][kp] = a1;
            float a2 = s_c[m][k + 1];  s_c[m][k + 1]  = s_c[m][kp];  s_c[m][kp]  = a2;
          }
        } else {
          // ---- case C: trailing swap; snapshot-consistent global writeback -
          if (tid >= pend && tid < NF) {
            if (tid == kp) {
              A[(size_t)kp * NF + kp] = 0.f;
            } else {
              float pvv = P[tid * PP + lc1];
              gvr = A[(size_t)tid * NF + kp];
              A[(size_t)tid * NF + kp] = pvv;
              A[(size_t)kp * NF + tid] = -pvv;
            }
          } else if (tid >= NF && tid < NF + WP) {
            int c = tid - NF;
            s_oldrow[c] = P[kp * PP + c];
            P[kp * PP + c] = P[(k + 1) * PP + c];
          } else if (tid >= NF + 24 && tid < NF + 24 + mp) {
            int m = tid - (NF + 24);
            float a1 = s_nu[m][k + 1]; s_nu[m][k + 1] = s_nu[m][kp]; s_nu[m][kp] = a1;
            float a2 = s_c[m][k + 1];  s_c[m][k + 1]  = s_c[m][kp];  s_c[m][kp]  = a2;
          }
        }
        __syncthreads();                                 // B2
        // ---- restage (post-swap; corrections use post-swap entries) ----
        if (tid > k + 1 && tid < NF) {
          float vpost = (tid == kp) ? pivdef_raw : vk;
          float cc;
          if (inpanel)          cc = P[tid * PP + lc1];
          else if (tid < pend)  cc = -s_oldrow[tid - k0];
          else if (tid == kp)   cc = -s_oldrow[lc1];
          else                  cc = gvr;
#pragma unroll
          for (int m = 0; m < mp; ++m) {
            float nu_i = s_nu[m][tid], c_i = s_c[m][tid];
            float im = iv[m];
            cc = fmaf(nu_i, im * s_c[m][k + 1], fmaf(-c_i, im * s_nu[m][k + 1], cc));
          }
          s_nu[mp][tid] = -vpost; s_c[mp][tid] = cc;
        }
        __syncthreads();                                 // B3
      }
    }
    __syncthreads();   // all pairs staged before trailing pass

    // ---- panel-end: j-outer rank-8 x2 streaming update of trailing block --
    if (pend < NF) {
      const int ty = tid >> 6, tx = tid & 63;
      const int nch = (NF - pend) >> 2;
#pragma unroll
      for (int g = 0; g < 2; ++g) {
        for (int jb = 0; jb < nch; jb += 64) {
          const int j4 = jb + tx;
          if (j4 < nch) {
            const int j = pend + (j4 << 2);
            float4 cj[4], tj[4];
#pragma unroll
            for (int m = 0; m < 4; ++m) {
              const int mm = g * 4 + m;
              const float im = iv[mm];
              float4 n4 = *(const float4*)(&s_nu[mm][j]);
              cj[m] = *(const float4*)(&s_c[mm][j]);
              tj[m] = make_float4(n4.x * im, n4.y * im, n4.z * im, n4.w * im);
            }
#pragma unroll 2
            for (int i = pend + ty; i < NF; i += 8) {
              float* ap = A + (size_t)i * NF + j;
              float4 a = *(float4*)ap;
#pragma unroll
              for (int m = 0; m < 4; ++m) {
                const int mm = g * 4 + m;
                const float ti = s_nu[mm][i] * iv[mm];
                const float ci = s_c[mm][i];
                a.x = fmaf(ti, cj[m].x, fmaf(-ci, tj[m].x, a.x));
                a.y = fmaf(ti, cj[m].y, fmaf(-ci, tj[m].y, a.y));
                a.z = fmaf(ti, cj[m].z, fmaf(-ci, tj[m].z, a.z));
                a.w = fmaf(ti, cj[m].w, fmaf(-ci, tj[m].w, a.w));
              }
              *(float4*)ap = a;
            }
          }
        }
      }
    }
    __syncthreads();   // trailing writes visible to next panel load
  }

  if (tid == 0) { out[b] = sign; out[NB + b] = logabs; }
}

extern "C" void kernel_launch(void* const* d_in, const int* in_sizes, int n_in,
                              void* d_out, int out_size, void* d_ws, size_t ws_size,
                              hipStream_t stream) {
  const float* U  = (const float*)d_in[0];
  const float* J  = (const float*)d_in[1];
  const int* idx  = (const int*)d_in[2];
  float* out = (float*)d_out;
  float* ws = (float*)d_ws;

  float* Ja  = ws;                          // 480*480
  float* Tmp = Ja + (size_t)NM * NM;        // 32*256*480
  float* Ff  = Tmp + (size_t)NB * NE * NM;  // 32*288*288

  build_ja_k<<<dim3(256), dim3(256), 0, stream>>>(J, Ja);
  gemm1_k<<<dim3(8, 4, NB), dim3(256), 0, stream>>>(U, idx, Ja, Tmp);
  gemm2_k<<<dim3(4, 4, NB), dim3(256), 0, stream>>>(U, idx, Tmp, Ff);
  fill_edges_k<<<dim3(NB), dim3(256), 0, stream>>>(U, idx, Ff);
  pfpanel_k<<<dim3(NB), dim3(512), 0, stream>>>(Ff, out);
}